// Round 5
// baseline (7450.687 us; speedup 1.0000x reference)
//
#include <hip/hip_runtime.h>
#include <math.h>

#define NB 128
#define NP 196
#define NENC 2048
#define NE 512
#define ND 512
#define NA 512
#define NV 10000
#define NVPAD 10112
#define NL 52
#define NT 51
#define KXH 3072   // [emb 512 | attw 2048 | h 512]

typedef unsigned short u16;
typedef __attribute__((ext_vector_type(8))) short bf16x8;
typedef __attribute__((ext_vector_type(8))) unsigned short u16x8;
typedef __attribute__((ext_vector_type(4))) unsigned short u16x4;
typedef __attribute__((ext_vector_type(4))) float f32x4;

#define MFMA16 __builtin_amdgcn_mfma_f32_16x16x32_bf16

__device__ __forceinline__ float sigmoidf_(float v) { return 1.0f / (1.0f + __expf(-v)); }
__device__ __forceinline__ float b2f(u16 u) { return __uint_as_float(((unsigned int)u) << 16); }
__device__ __forceinline__ u16 f2b(float f) {
  unsigned int u = __float_as_uint(f);
  unsigned int r = (u + 0x7FFFu + ((u >> 16) & 1u)) >> 16;
  return (u16)r;
}

// ---------------- two-level grid barrier (monotonic epochs) ----------------
// bar[g*16] g=0..7 : leaf counters (64B apart); bar[128]: root; bar[160]: release
__device__ __forceinline__ void gsync(unsigned int* bar, int bid, int k) {
  __syncthreads();
  if (threadIdx.x == 0) {
    __threadfence();  // release this block's writes to agent scope
    int g = bid & 7;
    unsigned int prev = __hip_atomic_fetch_add(&bar[g * 16], 1u, __ATOMIC_ACQ_REL,
                                               __HIP_MEMORY_SCOPE_AGENT);
    if (prev == (unsigned int)(k * 32 + 31)) {        // last of this leaf group
      unsigned int pr = __hip_atomic_fetch_add(&bar[128], 1u, __ATOMIC_ACQ_REL,
                                               __HIP_MEMORY_SCOPE_AGENT);
      if (pr == (unsigned int)(k * 8 + 7)) {          // last group -> release
        __hip_atomic_store(&bar[160], (unsigned int)(k + 1), __ATOMIC_RELEASE,
                           __HIP_MEMORY_SCOPE_AGENT);
      }
    }
    while (__hip_atomic_load(&bar[160], __ATOMIC_RELAXED, __HIP_MEMORY_SCOPE_AGENT)
           < (unsigned int)(k + 1)) {
      __builtin_amdgcn_s_sleep(2);
    }
    __threadfence();  // acquire: invalidate so we see other blocks' writes
  }
  __syncthreads();
}

// ---------------- sort (stable, descending) + nact[t] ----------------
__global__ void kSort(const int* __restrict__ cap_len, const int* __restrict__ captions,
                      int* __restrict__ order, int* __restrict__ nact,
                      float* __restrict__ out_cap, float* __restrict__ out_dlen) {
  __shared__ int lens[NB];
  __shared__ int s_dl[NB];
  int tid = threadIdx.x;
  lens[tid] = cap_len[tid];
  __syncthreads();
  int li = lens[tid];
  int r = 0;
  for (int j = 0; j < NB; ++j) {
    int lj = lens[j];
    if (lj > li || (lj == li && j < tid)) r++;
  }
  order[r] = tid;
  s_dl[r] = li - 1;
  out_dlen[r] = (float)(li - 1);
  for (int l = 0; l < NL; ++l)
    out_cap[(size_t)r * NL + l] = (float)captions[(size_t)tid * NL + l];
  __syncthreads();
  if (tid < NT) {
    int cnt = 0;
    for (int j = 0; j < NB; ++j) cnt += (s_dl[j] > tid) ? 1 : 0;
    nact[tid] = cnt;
  }
}

// ---------------- zero alphas for inactive (b,t) upfront ----------------
__global__ void kAlphaZero(const int* __restrict__ nact, float* __restrict__ out_alph) {
  int t = blockIdx.x;
  int n0 = nact[t];
  int cnt = (NB - n0) * NP;
  for (int i = threadIdx.x; i < cnt; i += 256) {
    int b = n0 + i / NP;
    int p = i - (i / NP) * NP;
    out_alph[((size_t)b * NT + t) * NP + p] = 0.0f;
  }
}

// ---------------- features: gather sorted + f32 -> bf16 ----------------
__global__ void kFeats(const float* __restrict__ features, const int* __restrict__ order,
                       u16* __restrict__ featsb) {
  int p = blockIdx.x, b = blockIdx.y, tid = threadIdx.x;
  const float* src = features + ((size_t)order[b] * NP + p) * NENC + tid * 8;
  u16* dst = featsb + ((size_t)b * NP + p) * NENC + tid * 8;
  float4 v0 = *(const float4*)src;
  float4 v1 = *(const float4*)(src + 4);
  u16x8 o;
  o[0] = f2b(v0.x); o[1] = f2b(v0.y); o[2] = f2b(v0.z); o[3] = f2b(v0.w);
  o[4] = f2b(v1.x); o[5] = f2b(v1.y); o[6] = f2b(v1.z); o[7] = f2b(v1.w);
  *(u16x8*)dst = o;
}

// ---------------- weight transposes (one-time) ----------------
__global__ void kTWenc(const float* __restrict__ W, u16* __restrict__ dst) {
  int n = blockIdx.x;
  for (int k = threadIdx.x; k < NENC; k += 256)
    dst[(size_t)n * NENC + k] = f2b(W[(size_t)k * NA + n]);
}
__global__ void kTdg(const float* __restrict__ Wdec, const float* __restrict__ Wbeta,
                     u16* __restrict__ dst) {
  int n = blockIdx.x;  // 2560
  for (int k = threadIdx.x; k < ND; k += 256) {
    float v = (n < NA) ? Wdec[(size_t)k * NA + n] : Wbeta[(size_t)k * NENC + (n - NA)];
    dst[(size_t)n * ND + k] = f2b(v);
  }
}
__global__ void kTifgo(const float* __restrict__ Wih, const float* __restrict__ Whh,
                       u16* __restrict__ dst) {
  int n = blockIdx.x;  // 2048 (d = n>>2, gate = n&3)
  int col = (n & 3) * ND + (n >> 2);
  for (int k = threadIdx.x; k < KXH; k += 256) {
    float v = (k < NE + NENC) ? Wih[(size_t)k * (4 * ND) + col]
                              : Whh[(size_t)(k - NE - NENC) * (4 * ND) + col];
    dst[(size_t)n * KXH + k] = f2b(v);
  }
}
__global__ void kTfc(const float* __restrict__ Wfc, u16* __restrict__ dst) {
  int n = blockIdx.x;  // NVPAD
  for (int k = threadIdx.x; k < ND; k += 256) {
    float v = (n < NV) ? Wfc[(size_t)k * NV + n] : 0.0f;
    dst[(size_t)n * ND + k] = f2b(v);
  }
}

// ---------------- eo = mean over P ----------------
__global__ void kEo(const u16* __restrict__ featsb, float* __restrict__ eo) {
  int e = blockIdx.x * 256 + threadIdx.x;
  int b = blockIdx.y;
  const u16* f = featsb + (size_t)b * NP * NENC + e;
  float s = 0.0f;
  for (int p = 0; p < NP; ++p) s += b2f(f[(size_t)p * NENC]);
  eo[(size_t)b * NENC + e] = s * (1.0f / NP);
}

// ---------------- h0 / c0 ----------------
__global__ void kInitHC(const float* __restrict__ eo,
                        const float* __restrict__ W_h0, const float* __restrict__ b_h0,
                        const float* __restrict__ W_c0, const float* __restrict__ b_c0,
                        u16* __restrict__ hb, u16* __restrict__ xh0, float* __restrict__ c) {
  __shared__ float s_eo[NENC];
  int b = blockIdx.y;
  for (int i = threadIdx.x; i < NENC; i += 256) s_eo[i] = eo[(size_t)b * NENC + i];
  __syncthreads();
  int d = blockIdx.x * 256 + threadIdx.x;
  const float* W = blockIdx.z ? W_c0 : W_h0;
  const float* bias = blockIdx.z ? b_c0 : b_h0;
  float acc = bias[d];
  for (int k = 0; k < NENC; ++k) acc += s_eo[k] * W[(size_t)k * ND + d];
  if (blockIdx.z) {
    c[(size_t)b * ND + d] = acc;
  } else {
    u16 hv = f2b(acc);
    hb[(size_t)b * ND + d] = hv;
    xh0[(size_t)b * KXH + NE + NENC + d] = hv;
  }
}

// ---------------- enc_proj (MFMA, bf16 out), 2-deep A prefetch ----------------
__global__ __launch_bounds__(256) void kEncProj(const u16* __restrict__ A,
                                                const u16* __restrict__ BT,
                                                const float* __restrict__ bias,
                                                u16* __restrict__ D) {
  int bid = blockIdx.x;
  int cc = bid & 7;
  int k = bid >> 3;
  int mt = cc * 25 + (k >> 3);
  if (mt >= 196) return;
  int ntile = k & 7;
  int w = threadIdx.x >> 6, lane = threadIdx.x & 63;
  int lr = lane & 15, lg = lane >> 4;
  int mb = mt * 128 + w * 32;
  int nb = ntile * 64;
  f32x4 acc[2][4] = {};
  const u16* a0 = A + (size_t)(mb + lr) * NENC + lg * 8;
  const u16* a1 = a0 + 16 * NENC;
  const u16* b0 = BT + (size_t)(nb + lr) * NENC + lg * 8;
  bf16x8 c0 = *(const bf16x8*)(a0);
  bf16x8 c1 = *(const bf16x8*)(a1);
  bf16x8 n0 = *(const bf16x8*)(a0 + 32);
  bf16x8 n1 = *(const bf16x8*)(a1 + 32);
  for (int k0 = 0; k0 < NENC; k0 += 64) {
    bf16x8 f0 = c0, f1 = c1;
    if (k0 + 64 < NENC) { c0 = *(const bf16x8*)(a0 + k0 + 64); c1 = *(const bf16x8*)(a1 + k0 + 64); }
#pragma unroll
    for (int nt = 0; nt < 4; ++nt) {
      bf16x8 bf = *(const bf16x8*)(b0 + (size_t)nt * 16 * NENC + k0);
      acc[0][nt] = MFMA16(f0, bf, acc[0][nt], 0, 0, 0);
      acc[1][nt] = MFMA16(f1, bf, acc[1][nt], 0, 0, 0);
    }
    bf16x8 g0 = n0, g1 = n1;
    if (k0 + 96 < NENC) { n0 = *(const bf16x8*)(a0 + k0 + 96); n1 = *(const bf16x8*)(a1 + k0 + 96); }
#pragma unroll
    for (int nt = 0; nt < 4; ++nt) {
      bf16x8 bf = *(const bf16x8*)(b0 + (size_t)nt * 16 * NENC + k0 + 32);
      acc[0][nt] = MFMA16(g0, bf, acc[0][nt], 0, 0, 0);
      acc[1][nt] = MFMA16(g1, bf, acc[1][nt], 0, 0, 0);
    }
  }
#pragma unroll
  for (int mt2 = 0; mt2 < 2; ++mt2)
#pragma unroll
    for (int nt = 0; nt < 4; ++nt)
#pragma unroll
      for (int j = 0; j < 4; ++j) {
        int row = mb + mt2 * 16 + lg * 4 + j;
        int col = nb + nt * 16 + lr;
        D[(size_t)row * NA + col] = f2b(acc[mt2][nt][j] + bias[col]);
      }
}

// ---------------- persistent loop kernel: all 51 steps, 3 grid barriers/step ----------------
__global__ __launch_bounds__(256, 1) void kLoop(
    const u16* __restrict__ featsb, const u16* __restrict__ encb,
    const u16* __restrict__ WdgT, const u16* __restrict__ WifgoT,
    const float* __restrict__ b_dec, const float* __restrict__ b_beta,
    const float* __restrict__ b_ih, const float* __restrict__ b_hh,
    const float* __restrict__ w_full, const float* __restrict__ b_full,
    const float* __restrict__ emb, const int* __restrict__ captions,
    const int* __restrict__ order, const int* __restrict__ nact,
    float* __restrict__ cst, u16* __restrict__ hb,
    u16* xh0, u16* xh1, u16* __restrict__ hnewAll,
    float* __restrict__ dec_proj, float* __restrict__ gate_raw,
    float* __restrict__ out_alph, unsigned int* bar) {
  __shared__ float smem[4][32][33];            // 16.9 KB; aliased by phase B below
  float* s_base = &smem[0][0][0];
  float* s_dp = s_base;                        // 512
  float* s_wf = s_base + 512;                  // 512
  float* s_al = s_base + 1024;                 // 256 (196 used)
  float* red  = s_base + 1280;                 // 16

  int bid = blockIdx.x, tid = threadIdx.x;
  int w = tid >> 6, lane = tid & 63;
  int lr = lane & 15, lg = lane >> 4;
  int barK = 0;
  u16* xha = xh0;
  u16* xhb = xh1;
  float bf_ = b_full[0];

  for (int t = 0; t < NT; ++t) {
    int nact_t = nact[t];

    // ===== phase A: dec_proj[128,512] & gate_raw[128,2048] = h @ WdgT =====
    {
      int tile = w * 256 + bid;                // 320 tiles of 32x32
      if (tile < 320) {
        int rt = tile & 3, ct = tile >> 2;
        int mb = rt * 32, nb = ct * 32;
        if (mb < nact_t) {
          f32x4 acc[2][2] = {};
          const u16* pa0 = hb + (size_t)(mb + lr) * ND + lg * 8;
          const u16* pa1 = pa0 + 16 * ND;
          const u16* pb0 = WdgT + (size_t)(nb + lr) * ND + lg * 8;
          const u16* pb1 = pb0 + 16 * ND;
#pragma unroll 4
          for (int k0 = 0; k0 < ND; k0 += 32) {
            bf16x8 af0 = *(const bf16x8*)(pa0 + k0);
            bf16x8 af1 = *(const bf16x8*)(pa1 + k0);
            bf16x8 bv0 = *(const bf16x8*)(pb0 + k0);
            bf16x8 bv1 = *(const bf16x8*)(pb1 + k0);
            acc[0][0] = MFMA16(af0, bv0, acc[0][0], 0, 0, 0);
            acc[1][0] = MFMA16(af1, bv0, acc[1][0], 0, 0, 0);
            acc[0][1] = MFMA16(af0, bv1, acc[0][1], 0, 0, 0);
            acc[1][1] = MFMA16(af1, bv1, acc[1][1], 0, 0, 0);
          }
#pragma unroll
          for (int m2 = 0; m2 < 2; ++m2)
#pragma unroll
            for (int n2 = 0; n2 < 2; ++n2)
#pragma unroll
              for (int j = 0; j < 4; ++j) {
                int row = mb + m2 * 16 + lg * 4 + j;
                int n = nb + n2 * 16 + lr;
                if (n < NA)
                  dec_proj[(size_t)row * NA + n] = acc[m2][n2][j] + b_dec[n];
                else
                  gate_raw[(size_t)row * NENC + (n - NA)] = acc[m2][n2][j] + b_beta[n - NA];
              }
        }
      }
    }
    gsync(bar, bid, barK++);

    // ===== phase B: scores + softmax + attw + x build (2 blocks per batch) =====
    {
      int b = bid >> 1, r = bid & 1;
      if (b < nact_t) {
        for (int i = tid; i < NA; i += 256) {
          s_dp[i] = dec_proj[(size_t)b * NA + i];
          s_wf[i] = w_full[i];
        }
        __syncthreads();
        for (int p = w; p < NP; p += 4) {
          const u16* ep = encb + ((size_t)b * NP + p) * NA + lane * 8;
          u16x8 v = *(const u16x8*)ep;
          float acc = 0.0f;
#pragma unroll
          for (int j = 0; j < 8; ++j) {
            int a = lane * 8 + j;
            float vv = b2f(v[j]) + s_dp[a];
            acc += fmaxf(vv, 0.0f) * s_wf[a];
          }
#pragma unroll
          for (int off = 32; off; off >>= 1) acc += __shfl_down(acc, off);
          if (lane == 0) s_al[p] = acc + bf_;
        }
        __syncthreads();
        float mx = -3.4e38f;
        for (int p = tid; p < NP; p += 256) mx = fmaxf(mx, s_al[p]);
#pragma unroll
        for (int off = 32; off; off >>= 1) mx = fmaxf(mx, __shfl_down(mx, off));
        if (lane == 0) red[w] = mx;
        __syncthreads();
        if (tid == 0) red[0] = fmaxf(fmaxf(red[0], red[1]), fmaxf(red[2], red[3]));
        __syncthreads();
        float m2v = red[0];
        float sm = 0.0f;
        for (int p = tid; p < NP; p += 256) {
          float e = __expf(s_al[p] - m2v);
          s_al[p] = e;
          sm += e;
        }
#pragma unroll
        for (int off = 32; off; off >>= 1) sm += __shfl_down(sm, off);
        if (lane == 0) red[8 + w] = sm;
        __syncthreads();
        if (tid == 0) red[8] = 1.0f / (red[8] + red[9] + red[10] + red[11]);
        __syncthreads();
        float inv = red[8];
        for (int p = tid; p < NP; p += 256) {
          float al = s_al[p] * inv;
          s_al[p] = al;
          if (r == 0) out_alph[((size_t)b * NT + t) * NP + p] = al;
        }
        if (r == 0) {
          int tok = captions[(size_t)order[b] * NL + t];
          int e = tid * 2;
          unsigned int w0 = (unsigned int)f2b(emb[(size_t)tok * NE + e]) |
                            ((unsigned int)f2b(emb[(size_t)tok * NE + e + 1]) << 16);
          *(unsigned int*)(xha + (size_t)b * KXH + e) = w0;
        }
        __syncthreads();
        int e0 = r * 1024 + tid * 4;
        float ac0 = 0.f, ac1 = 0.f, ac2 = 0.f, ac3 = 0.f;
        const u16* fb = featsb + (size_t)b * NP * NENC + e0;
#pragma unroll 4
        for (int p = 0; p < NP; ++p) {
          u16x4 v4 = *(const u16x4*)(fb + (size_t)p * NENC);
          float al = s_al[p];
          ac0 += al * b2f(v4[0]);
          ac1 += al * b2f(v4[1]);
          ac2 += al * b2f(v4[2]);
          ac3 += al * b2f(v4[3]);
        }
        const float* gr = gate_raw + (size_t)b * NENC + e0;
        u16x4 o4;
        o4[0] = f2b(ac0 * sigmoidf_(gr[0]));
        o4[1] = f2b(ac1 * sigmoidf_(gr[1]));
        o4[2] = f2b(ac2 * sigmoidf_(gr[2]));
        o4[3] = f2b(ac3 * sigmoidf_(gr[3]));
        *(u16x4*)(xha + (size_t)b * KXH + NE + e0) = o4;
      }
    }
    gsync(bar, bid, barK++);

    // ===== phase C: gates GEMM (256 x 32x32 tiles, 4-way K-split) + LSTM =====
    {
      int rt = bid & 3, ct = bid >> 2;
      int mb = rt * 32, nb = ct * 32;
      if (mb < nact_t) {
        f32x4 acc[2][2] = {};
        const u16* pa0 = xha + (size_t)(mb + lr) * KXH + w * 768 + lg * 8;
        const u16* pa1 = pa0 + 16 * KXH;
        const u16* pb0 = WifgoT + (size_t)(nb + lr) * KXH + w * 768 + lg * 8;
        const u16* pb1 = pb0 + 16 * KXH;
#pragma unroll 4
        for (int k0 = 0; k0 < 768; k0 += 32) {
          bf16x8 af0 = *(const bf16x8*)(pa0 + k0);
          bf16x8 af1 = *(const bf16x8*)(pa1 + k0);
          bf16x8 bv0 = *(const bf16x8*)(pb0 + k0);
          bf16x8 bv1 = *(const bf16x8*)(pb1 + k0);
          acc[0][0] = MFMA16(af0, bv0, acc[0][0], 0, 0, 0);
          acc[1][0] = MFMA16(af1, bv0, acc[1][0], 0, 0, 0);
          acc[0][1] = MFMA16(af0, bv1, acc[0][1], 0, 0, 0);
          acc[1][1] = MFMA16(af1, bv1, acc[1][1], 0, 0, 0);
        }
#pragma unroll
        for (int m2 = 0; m2 < 2; ++m2)
#pragma unroll
          for (int n2 = 0; n2 < 2; ++n2)
#pragma unroll
            for (int j = 0; j < 4; ++j)
              smem[w][m2 * 16 + lg * 4 + j][n2 * 16 + lr] = acc[m2][n2][j];
      }
      __syncthreads();
      int row = tid >> 3, dl = tid & 7;
      int grow = mb + row;
      int d = ct * 8 + dl;
      size_t off = (size_t)grow * ND + d;
      if (mb < nact_t && grow < nact_t) {
        int cl = dl * 4;
        float g0 = smem[0][row][cl + 0] + smem[1][row][cl + 0] + smem[2][row][cl + 0] + smem[3][row][cl + 0];
        float g1 = smem[0][row][cl + 1] + smem[1][row][cl + 1] + smem[2][row][cl + 1] + smem[3][row][cl + 1];
        float g2 = smem[0][row][cl + 2] + smem[1][row][cl + 2] + smem[2][row][cl + 2] + smem[3][row][cl + 2];
        float g3 = smem[0][row][cl + 3] + smem[1][row][cl + 3] + smem[2][row][cl + 3] + smem[3][row][cl + 3];
        float gi = g0 + b_ih[d] + b_hh[d];
        float gf = g1 + b_ih[ND + d] + b_hh[ND + d];
        float gg = g2 + b_ih[2 * ND + d] + b_hh[2 * ND + d];
        float go = g3 + b_ih[3 * ND + d] + b_hh[3 * ND + d];
        float cn = sigmoidf_(gf) * cst[off] + sigmoidf_(gi) * tanhf(gg);
        float hn = sigmoidf_(go) * tanhf(cn);
        u16 hv = f2b(hn);
        cst[off] = cn;
        hb[off] = hv;
        hnewAll[(size_t)t * NB * ND + off] = hv;
        xhb[(size_t)grow * KXH + NE + NENC + d] = hv;
      } else {
        xhb[(size_t)grow * KXH + NE + NENC + d] = hb[off];  // carry frozen h
      }
    }
    gsync(bar, bid, barK++);
    u16* tmp = xha; xha = xhb; xhb = tmp;
  }
}

// ---------------- batched preds GEMM (post-loop) ----------------
__global__ __launch_bounds__(256) void kPredsAll(const u16* __restrict__ hnewAll,
                                                 const u16* __restrict__ BT,
                                                 const float* __restrict__ b_fc,
                                                 const int* __restrict__ nact,
                                                 float* __restrict__ out_pred) {
  int t = blockIdx.y;
  int nact_t = nact[t];
  int w = threadIdx.x >> 6, lane = threadIdx.x & 63;
  int lr = lane & 15, lg = lane >> 4;
  int mb = w * 32;
  int nb = blockIdx.x * 64;
  f32x4 acc[2][4] = {};
  if (mb < nact_t) {
    const u16* a0 = hnewAll + (size_t)t * NB * ND + (size_t)(mb + lr) * ND + lg * 8;
    const u16* a1 = a0 + 16 * ND;
    const u16* b0 = BT + (size_t)(nb + lr) * ND + lg * 8;
    for (int k0 = 0; k0 < ND; k0 += 32) {
      bf16x8 af0 = *(const bf16x8*)(a0 + k0);
      bf16x8 af1 = *(const bf16x8*)(a1 + k0);
#pragma unroll
      for (int nt = 0; nt < 4; ++nt) {
        bf16x8 bf = *(const bf16x8*)(b0 + (size_t)nt * 16 * ND + k0);
        acc[0][nt] = MFMA16(af0, bf, acc[0][nt], 0, 0, 0);
        acc[1][nt] = MFMA16(af1, bf, acc[1][nt], 0, 0, 0);
      }
    }
  }
#pragma unroll
  for (int mt = 0; mt < 2; ++mt)
#pragma unroll
    for (int nt = 0; nt < 4; ++nt)
#pragma unroll
      for (int j = 0; j < 4; ++j) {
        int gn = nb + nt * 16 + lr;
        if (gn < NV) {
          int row = mb + mt * 16 + lg * 4 + j;
          float v = (row < nact_t) ? (acc[mt][nt][j] + b_fc[gn]) : 0.0f;
          __builtin_nontemporal_store(v, &out_pred[((size_t)row * NT + t) * NV + gn]);
        }
      }
}

extern "C" void kernel_launch(void* const* d_in, const int* in_sizes, int n_in,
                              void* d_out, int out_size, void* d_ws, size_t ws_size,
                              hipStream_t stream) {
  (void)in_sizes; (void)n_in; (void)out_size; (void)ws_size;
  const float* features  = (const float*)d_in[0];
  const int*   captions  = (const int*)d_in[1];
  const int*   cap_len   = (const int*)d_in[2];
  const float* emb       = (const float*)d_in[3];
  const float* W_enc_att = (const float*)d_in[4];
  const float* b_enc_att = (const float*)d_in[5];
  const float* W_dec_att = (const float*)d_in[6];
  const float* b_dec_att = (const float*)d_in[7];
  const float* w_full    = (const float*)d_in[8];
  const float* b_full    = (const float*)d_in[9];
  const float* W_h0      = (const float*)d_in[10];
  const float* b_h0      = (const float*)d_in[11];
  const float* W_c0      = (const float*)d_in[12];
  const float* b_c0      = (const float*)d_in[13];
  const float* W_beta    = (const float*)d_in[14];
  const float* b_beta    = (const float*)d_in[15];
  const float* W_ih      = (const float*)d_in[16];
  const float* b_ih      = (const float*)d_in[17];
  const float* W_hh      = (const float*)d_in[18];
  const float* b_hh      = (const float*)d_in[19];
  const float* W_fc      = (const float*)d_in[20];
  const float* b_fc      = (const float*)d_in[21];

  float* out      = (float*)d_out;
  float* out_pred = out;
  float* out_cap  = out_pred + (size_t)NB * NT * NV;
  float* out_dlen = out_cap + (size_t)NB * NL;
  float* out_alph = out_dlen + NB;

  char* p = (char*)d_ws;
  auto alloc = [&](size_t nbytes) { void* r = (void*)p; p += (nbytes + 255) & ~(size_t)255; return r; };
  int*   order    = (int*)alloc(NB * 4);
  int*   nact     = (int*)alloc(NT * 4);
  unsigned int* bar = (unsigned int*)alloc(1024);
  float* eo       = (float*)alloc((size_t)NB * NENC * 4);
  float* c        = (float*)alloc((size_t)NB * ND * 4);
  u16*   hb       = (u16*)alloc((size_t)NB * ND * 2);
  u16*   xh0      = (u16*)alloc((size_t)NB * KXH * 2);
  u16*   xh1      = (u16*)alloc((size_t)NB * KXH * 2);
  u16*   hnewAll  = (u16*)alloc((size_t)NT * NB * ND * 2);
  float* dec_proj = (float*)alloc((size_t)NB * NA * 4);
  float* gate_raw = (float*)alloc((size_t)NB * NENC * 4);
  u16*   featsb   = (u16*)alloc((size_t)NB * NP * NENC * 2);
  u16*   encb     = (u16*)alloc((size_t)NB * NP * NA * 2);
  u16*   WencT    = (u16*)alloc((size_t)NA * NENC * 2);
  u16*   WdgT     = (u16*)alloc((size_t)(NA + NENC) * ND * 2);
  u16*   WifgoT   = (u16*)alloc((size_t)(4 * ND) * KXH * 2);
  u16*   WfcT     = (u16*)alloc((size_t)NVPAD * ND * 2);

  hipMemsetAsync(bar, 0, 1024, stream);
  kSort<<<1, NB, 0, stream>>>(cap_len, captions, order, nact, out_cap, out_dlen);
  kAlphaZero<<<NT, 256, 0, stream>>>(nact, out_alph);
  kFeats<<<dim3(NP, NB), 256, 0, stream>>>(features, order, featsb);
  kTWenc<<<NA, 256, 0, stream>>>(W_enc_att, WencT);
  kTdg<<<NA + NENC, 256, 0, stream>>>(W_dec_att, W_beta, WdgT);
  kTifgo<<<4 * ND, 256, 0, stream>>>(W_ih, W_hh, WifgoT);
  kTfc<<<NVPAD, 256, 0, stream>>>(W_fc, WfcT);
  kEo<<<dim3(NENC / 256, NB), 256, 0, stream>>>(featsb, eo);
  kInitHC<<<dim3(ND / 256, NB, 2), 256, 0, stream>>>(eo, W_h0, b_h0, W_c0, b_c0, hb, xh0, c);
  kEncProj<<<1600, 256, 0, stream>>>(featsb, WencT, b_enc_att, encb);

  kLoop<<<256, 256, 0, stream>>>(featsb, encb, WdgT, WifgoT,
                                 b_dec_att, b_beta, b_ih, b_hh, w_full, b_full,
                                 emb, captions, order, nact,
                                 c, hb, xh0, xh1, hnewAll,
                                 dec_proj, gate_raw, out_alph, bar);

  kPredsAll<<<dim3(NVPAD / 64, NT), 256, 0, stream>>>(hnewAll, WfcT, b_fc, nact, out_pred);
}